// Round 1
// baseline (14996.780 us; speedup 1.0000x reference)
//
#include <hip/hip_runtime.h>

// Problem constants
constexpr int B = 64, T = 1024, D = 128, H = 256;
// RNN partition: 16 groups x (4 batches); 16 blocks/group, 16 units/block
constexpr int NG = 16;   // groups
constexpr int GK = 16;   // blocks per group
constexpr int GB = 4;    // batches per group
constexpr int UPB = 16;  // hidden units per block

__device__ __forceinline__ float sigmoidf_(float v) {
    return 1.f / (1.f + __expf(-v));
}
__device__ __forceinline__ float tanhf_(float v) {
    float e2 = __expf(2.f * v);
    return 1.f - 2.f / (e2 + 1.f);
}

// ---------------- P1: per-(b,d) scan over t ----------------
// ffill/idelta are written into d_out used as scratch (fully overwritten later).
__global__ __launch_bounds__(128) void prep_scan(
    const float* __restrict__ x, const int* __restrict__ mask,
    const float* __restrict__ ts, const float* __restrict__ it0,
    float* __restrict__ ffill, float* __restrict__ idelta,
    float* __restrict__ mean, float* __restrict__ tdlv)
{
    const int b = blockIdx.x;
    const int d = threadIdx.x;
    float prev_x = 0.f, prev_td = 0.f, osum = 0.f, mcnt = 0.f;
    float prev_ts = it0[b];               // init_time is (1,B) -> flat[b]
    const int baseT = b * T;
    for (int t = 0; t < T; ++t) {
        float tsv = ts[baseT + t];
        float td = tsv - prev_ts;         // time_delta[b,t]
        prev_ts = tsv;
        int idx = (baseT + t) * D + d;
        int m = mask[idx];                // True(1) == missing
        float xv = x[idx];
        if (!m) { prev_x = xv; osum += xv; } else { mcnt += 1.f; }
        prev_td += td;
        ffill[idx]  = prev_x;
        idelta[idx] = prev_td;
        if (!m) prev_td = 0.f;
        if (d == 0) tdlv[baseT + t] = logf(fminf(fmaxf(td, 0.f), 1000.f));
    }
    mean[b * D + d] = osum / fmaxf(mcnt, 1.f);   // ref: sum(observed)/clip(count(missing),1)
}

// ---------------- P2: imputation matvec ----------------
constexpr int ROWS = 64;   // (b,t) rows per block
__global__ __launch_bounds__(256) void fill_kernel(
    const float* __restrict__ x, const int* __restrict__ mask,
    const float* __restrict__ ffill, const float* __restrict__ idelta,
    const float* __restrict__ mean, const float* __restrict__ idw,
    const float* __restrict__ idb, float* __restrict__ xf)
{
    __shared__ float widw[128 * 129];   // padded: bank-conflict-free (2-way aliasing only)
    __shared__ float ide[2][128];
    const int tid = threadIdx.x;
    for (int i = tid; i < 128 * 128; i += 256)
        widw[(i >> 7) * 129 + (i & 127)] = idw[i];
    __syncthreads();
    const int p = tid >> 7, d = tid & 127;
    const float bias = idb[d];
    const int row0 = blockIdx.x * ROWS;
    for (int r = 0; r < ROWS; r += 2) {
        const int rowp = row0 + r + p;    // b*T + t
        const int idx = rowp * D + d;
        ide[p][d] = fminf(fmaxf(idelta[idx] - 1.f, 0.f), 1000.f);  // clip(TIME_UNIT*(idelta-1),0,1000)
        __syncthreads();
        float acc = bias;
        #pragma unroll
        for (int k = 0; k < 128; ++k)
            acc = fmaf(ide[p][k], widw[d * 129 + k], acc);
        float fw = __expf(-fmaxf(acc, 0.f));
        float filled = ffill[idx] * fw + (1.f - fw) * mean[(rowp >> 10) * D + d];
        xf[idx] = mask[idx] ? filled : x[idx];
        __syncthreads();
    }
}

// ---------------- P3: persistent grouped GRU-D recurrence ----------------
__global__ __launch_bounds__(256, 1) void rnn_kernel(
    const float* __restrict__ xf, const float* __restrict__ tdlv,
    const float* __restrict__ w_ih, const float* __restrict__ w_hh,
    const float* __restrict__ b_ih, const float* __restrict__ b_hh,
    const float* __restrict__ hdw, const float* __restrict__ hdb,
    float* __restrict__ hbuf, unsigned int* __restrict__ cnt,
    float* __restrict__ out)
{
    const int tid = threadIdx.x;
    const int g  = blockIdx.x & (NG - 1);   // group (stride-16 members -> same XCD mod 8)
    const int kb = blockIdx.x >> 4;         // block-in-group: owns units [kb*16, kb*16+16)
    const int u_loc = tid >> 4;             // 0..15
    const int kc = tid & 15;                // k-chunk 0..15
    const int row = kb * UPB + u_loc;       // owned hidden unit
    const int b0 = g * GB;                  // first batch of group

    // Weight-stationary register slices
    float whr[16], whz[16], whn[16];
    #pragma unroll
    for (int j = 0; j < 16; ++j) {
        whr[j] = w_hh[(row        ) * H + kc * 16 + j];
        whz[j] = w_hh[(row +     H) * H + kc * 16 + j];
        whn[j] = w_hh[(row + 2 * H) * H + kc * 16 + j];
    }
    float wir[8], wiz[8], win_[8];
    #pragma unroll
    for (int j = 0; j < 8; ++j) {
        wir[j]  = w_ih[(row        ) * D + kc * 8 + j];
        wiz[j]  = w_ih[(row +     H) * D + kc * 8 + j];
        win_[j] = w_ih[(row + 2 * H) * D + kc * 8 + j];
    }
    const float hdwk = hdw[tid];   // decay params for k = tid
    const float hdbk = hdb[tid];
    float br = 0.f, bz = 0.f, bnx = 0.f, bnh = 0.f;
    if (kc == 0) {
        br  = b_ih[row] + b_hh[row];
        bz  = b_ih[H + row] + b_hh[H + row];
        bnx = b_ih[2 * H + row];
        bnh = b_hh[2 * H + row];
    }

    // decayed h staged per step; 17-padded chunks -> conflict-free reads
    __shared__ float hdec[GB][16 * 17];

    for (int t = 0; t < T; ++t) {
        const float* hin = hbuf + (t & 1) * (B * H);
        float* hout = hbuf + ((t & 1) ^ 1) * (B * H);

        // 1) decayed h into LDS (thread handles k = tid for all GB batches)
        #pragma unroll
        for (int bb = 0; bb < GB; ++bb) {
            float tdv = tdlv[(b0 + bb) * T + t];
            float dec = __expf(-fmaxf(tdv * hdwk + hdbk, 0.f));
            float hv = hin[(b0 + bb) * H + tid];
            hdec[bb][(tid >> 4) * 17 + (tid & 15)] = hv * dec;
        }
        __syncthreads();

        // 2) partial dot products (gi + gh fused; n-gate parts kept separate)
        float pr[GB], pz[GB], pnx[GB], pnh[GB];
        #pragma unroll
        for (int bb = 0; bb < GB; ++bb) {
            const float* xp = xf + (size_t)((b0 + bb) * T + t) * D + kc * 8;
            float a0 = 0.f, a1 = 0.f, a2 = 0.f, a3 = 0.f;
            #pragma unroll
            for (int j = 0; j < 8; ++j) {
                float xv = xp[j];
                a0 = fmaf(wir[j], xv, a0);
                a1 = fmaf(wiz[j], xv, a1);
                a2 = fmaf(win_[j], xv, a2);
            }
            #pragma unroll
            for (int j = 0; j < 16; ++j) {
                float hv = hdec[bb][kc * 17 + j];
                a0 = fmaf(whr[j], hv, a0);
                a1 = fmaf(whz[j], hv, a1);
                a3 = fmaf(whn[j], hv, a3);
            }
            pr[bb] = a0; pz[bb] = a1; pnx[bb] = a2; pnh[bb] = a3;
        }

        // 3) butterfly reduce over the 16 k-chunk lanes
        #pragma unroll
        for (int m = 1; m < 16; m <<= 1) {
            #pragma unroll
            for (int bb = 0; bb < GB; ++bb) {
                pr[bb]  += __shfl_xor(pr[bb],  m, 64);
                pz[bb]  += __shfl_xor(pz[bb],  m, 64);
                pnx[bb] += __shfl_xor(pnx[bb], m, 64);
                pnh[bb] += __shfl_xor(pnh[bb], m, 64);
            }
        }

        // 4) owner-lane epilogue
        if (kc == 0) {
            #pragma unroll
            for (int bb = 0; bb < GB; ++bb) {
                float hd = hdec[bb][kb * 17 + u_loc];   // decayed h of own unit
                float r = sigmoidf_(pr[bb] + br);
                float z = sigmoidf_(pz[bb] + bz);
                float n = tanhf_(pnx[bb] + bnx + r * (pnh[bb] + bnh));
                float hnew = (1.f - z) * n + z * hd;
                out[(size_t)((b0 + bb) * T + t) * H + row] = hnew;
                hout[(b0 + bb) * H + row] = hnew;
                if (t == T - 1)
                    out[(size_t)B * T * H + (b0 + bb) * H + row] = hnew;
            }
        }

        // 5) per-group inter-block barrier (fresh counter per step)
        if (t < T - 1) {
            __syncthreads();
            if (tid == 0) {
                __threadfence();   // release: flush dirty L2 to LLC (cross-XCD visibility)
                __hip_atomic_fetch_add(&cnt[t * NG + g], 1u,
                                       __ATOMIC_RELAXED, __HIP_MEMORY_SCOPE_AGENT);
                while (__hip_atomic_load(&cnt[t * NG + g],
                                         __ATOMIC_RELAXED, __HIP_MEMORY_SCOPE_AGENT) < (unsigned)GK)
                    __builtin_amdgcn_s_sleep(1);
                __threadfence();   // acquire: invalidate L1/L2 before reading others' h
            }
            __syncthreads();
        }
    }
}

extern "C" void kernel_launch(void* const* d_in, const int* in_sizes, int n_in,
                              void* d_out, int out_size, void* d_ws, size_t ws_size,
                              hipStream_t stream) {
    (void)in_sizes; (void)n_in; (void)out_size; (void)ws_size;
    const float* x    = (const float*)d_in[0];
    const int*   mask = (const int*)d_in[1];
    const float* ts   = (const float*)d_in[2];
    const float* it0  = (const float*)d_in[3];
    const float* w_ih = (const float*)d_in[4];
    const float* w_hh = (const float*)d_in[5];
    const float* b_ih = (const float*)d_in[6];
    const float* b_hh = (const float*)d_in[7];
    const float* idw  = (const float*)d_in[8];
    const float* idb  = (const float*)d_in[9];
    const float* hdw  = (const float*)d_in[10];
    const float* hdb  = (const float*)d_in[11];
    float* out = (float*)d_out;

    // Workspace layout (bytes)
    char* ws = (char*)d_ws;
    float* xf   = (float*)(ws);                         // B*T*D f32 = 33554432 B
    float* tdlv = (float*)(ws + 33554432);              // B*T f32   = 262144 B
    float* mean = (float*)(ws + 33816576);              // B*D f32   = 32768 B
    float* hbuf = (float*)(ws + 33849344);              // 2*B*H f32 = 131072 B
    unsigned int* cnt = (unsigned int*)(ws + 33980416); // T*NG u32  = 65536 B

    // d_out used as scratch before the RNN overwrites it entirely:
    float* ffill  = out;                       // B*T*D floats
    float* idelta = out + (size_t)B * T * D;   // B*T*D floats (fits: 2*B*T*D <= out_size)

    // zero h double-buffer + barrier counters (contiguous region)
    hipMemsetAsync(hbuf, 0, (size_t)(2 * B * H) * 4 + (size_t)(T * NG) * 4, stream);

    prep_scan<<<B, D, 0, stream>>>(x, mask, ts, it0, ffill, idelta, mean, tdlv);
    fill_kernel<<<(B * T) / ROWS, 256, 0, stream>>>(x, mask, ffill, idelta, mean, idw, idb, xf);
    rnn_kernel<<<NG * GK, 256, 0, stream>>>(xf, tdlv, w_ih, w_hh, b_ih, b_hh, hdw, hdb,
                                            hbuf, cnt, out);
}

// Round 2
// 4637.111 us; speedup vs baseline: 3.2341x; 3.2341x over previous
//
#include <hip/hip_runtime.h>

// Problem constants
constexpr int B = 64, T = 1024, D = 128, H = 256;
// RNN partition: 16 groups x (4 batches); 16 blocks/group, 16 units/block
constexpr int NG = 16;   // groups
constexpr int GK = 16;   // blocks per group
constexpr int GB = 4;    // batches per group
constexpr int UPB = 16;  // hidden units per block

__device__ __forceinline__ float sigmoidf_(float v) {
    return 1.f / (1.f + __expf(-v));
}
__device__ __forceinline__ float tanhf_(float v) {
    float e2 = __expf(2.f * v);
    return 1.f - 2.f / (e2 + 1.f);
}

// ---------------- P1: per-(b,d) scan over t ----------------
// ffill/idelta are written into d_out used as scratch (fully overwritten later).
__global__ __launch_bounds__(128) void prep_scan(
    const float* __restrict__ x, const int* __restrict__ mask,
    const float* __restrict__ ts, const float* __restrict__ it0,
    float* __restrict__ ffill, float* __restrict__ idelta,
    float* __restrict__ mean, float* __restrict__ tdlv)
{
    const int b = blockIdx.x;
    const int d = threadIdx.x;
    float prev_x = 0.f, prev_td = 0.f, osum = 0.f, mcnt = 0.f;
    float prev_ts = it0[b];               // init_time is (1,B) -> flat[b]
    const int baseT = b * T;
    for (int t = 0; t < T; ++t) {
        float tsv = ts[baseT + t];
        float td = tsv - prev_ts;         // time_delta[b,t]
        prev_ts = tsv;
        int idx = (baseT + t) * D + d;
        int m = mask[idx];                // True(1) == missing
        float xv = x[idx];
        if (!m) { prev_x = xv; osum += xv; } else { mcnt += 1.f; }
        prev_td += td;
        ffill[idx]  = prev_x;
        idelta[idx] = prev_td;
        if (!m) prev_td = 0.f;
        if (d == 0) tdlv[baseT + t] = logf(fminf(fmaxf(td, 0.f), 1000.f));
    }
    mean[b * D + d] = osum / fmaxf(mcnt, 1.f);
}

// ---------------- P2: imputation matvec ----------------
constexpr int ROWS = 64;   // (b,t) rows per block
__global__ __launch_bounds__(256) void fill_kernel(
    const float* __restrict__ x, const int* __restrict__ mask,
    const float* __restrict__ ffill, const float* __restrict__ idelta,
    const float* __restrict__ mean, const float* __restrict__ idw,
    const float* __restrict__ idb, float* __restrict__ xf)
{
    __shared__ float widw[128 * 129];   // padded: conflict-free
    __shared__ float ide[2][128];
    const int tid = threadIdx.x;
    for (int i = tid; i < 128 * 128; i += 256)
        widw[(i >> 7) * 129 + (i & 127)] = idw[i];
    __syncthreads();
    const int p = tid >> 7, d = tid & 127;
    const float bias = idb[d];
    const int row0 = blockIdx.x * ROWS;
    for (int r = 0; r < ROWS; r += 2) {
        const int rowp = row0 + r + p;    // b*T + t
        const int idx = rowp * D + d;
        ide[p][d] = fminf(fmaxf(idelta[idx] - 1.f, 0.f), 1000.f);
        __syncthreads();
        float acc = bias;
        #pragma unroll
        for (int k = 0; k < 128; ++k)
            acc = fmaf(ide[p][k], widw[d * 129 + k], acc);
        float fw = __expf(-fmaxf(acc, 0.f));
        float filled = ffill[idx] * fw + (1.f - fw) * mean[(rowp >> 10) * D + d];
        xf[idx] = mask[idx] ? filled : x[idx];
        __syncthreads();
    }
}

// ---------------- P3: persistent grouped GRU-D recurrence ----------------
// Fence-free cross-block h-exchange: each h value published as a 64-bit
// (tag | f32bits) relaxed agent-scope atomic to the LLC. Tag==t+1 marks
// step-t output. Double-buffered by t&1; tag disambiguates, max skew is 1
// step (a block cannot overwrite a slot until every peer posted the step
// that required reading it). No threadfence, no counters, no grid barrier.
__global__ __launch_bounds__(256, 1) void rnn_kernel(
    const float* __restrict__ xf, const float* __restrict__ tdlv,
    const float* __restrict__ w_ih, const float* __restrict__ w_hh,
    const float* __restrict__ b_ih, const float* __restrict__ b_hh,
    const float* __restrict__ hdw, const float* __restrict__ hdb,
    unsigned long long* __restrict__ hx, float* __restrict__ out)
{
    const int tid = threadIdx.x;
    const int g  = blockIdx.x & (NG - 1);
    const int kb = blockIdx.x >> 4;         // owns units [kb*16, kb*16+16)
    const int u_loc = tid >> 4;
    const int kc = tid & 15;
    const int row = kb * UPB + u_loc;
    const int b0 = g * GB;

    // Weight-stationary register slices
    float whr[16], whz[16], whn[16];
    #pragma unroll
    for (int j = 0; j < 16; ++j) {
        whr[j] = w_hh[(row        ) * H + kc * 16 + j];
        whz[j] = w_hh[(row +     H) * H + kc * 16 + j];
        whn[j] = w_hh[(row + 2 * H) * H + kc * 16 + j];
    }
    float wir[8], wiz[8], win_[8];
    #pragma unroll
    for (int j = 0; j < 8; ++j) {
        wir[j]  = w_ih[(row        ) * D + kc * 8 + j];
        wiz[j]  = w_ih[(row +     H) * D + kc * 8 + j];
        win_[j] = w_ih[(row + 2 * H) * D + kc * 8 + j];
    }
    const float hdwk = hdw[tid];   // decay params for staged unit k = tid
    const float hdbk = hdb[tid];
    float br = 0.f, bz = 0.f, bnx = 0.f, bnh = 0.f;
    if (kc == 0) {
        br  = b_ih[row] + b_hh[row];
        bz  = b_ih[H + row] + b_hh[H + row];
        bnx = b_ih[2 * H + row];
        bnh = b_hh[2 * H + row];
    }

    __shared__ float hdec[GB][16 * 17];   // decayed h, padded chunks
    __shared__ float hown[GB][16];        // own units' latest h (LDS shortcut)

    for (int i = tid; i < GB * 16 * 17; i += 256)
        ((float*)hdec)[i] = 0.f;          // h0 = 0 (decayed 0 is 0)
    __syncthreads();

    const bool ownk = ((tid >> 4) == kb); // staged unit k=tid belongs to this block

    for (int t = 0; t < T; ++t) {
        // ---- (a) gi partials first: independent of h, overlaps exchange ----
        float pr[GB], pz[GB], pnx[GB], pnh[GB];
        #pragma unroll
        for (int bb = 0; bb < GB; ++bb) {
            const float* xp = xf + (size_t)((b0 + bb) * T + t) * D + kc * 8;
            float a0 = 0.f, a1 = 0.f, a2 = 0.f;
            #pragma unroll
            for (int j = 0; j < 8; ++j) {
                float xv = xp[j];
                a0 = fmaf(wir[j], xv, a0);
                a1 = fmaf(wiz[j], xv, a1);
                a2 = fmaf(win_[j], xv, a2);
            }
            pr[bb] = a0; pz[bb] = a1; pnx[bb] = a2; pnh[bb] = 0.f; pnh[bb] = 0.f;
        }

        // ---- (b) stage decayed h[t-1] into LDS (thread stages unit k=tid) ----
        if (t > 0) {
            float hv[GB];
            if (ownk) {
                #pragma unroll
                for (int bb = 0; bb < GB; ++bb) hv[bb] = hown[bb][tid & 15];
            } else {
                const unsigned long long* src = hx + (size_t)((t - 1) & 1) * (B * H);
                unsigned long long v[GB];
                for (;;) {
                    bool ok = true;
                    #pragma unroll
                    for (int bb = 0; bb < GB; ++bb) {
                        v[bb] = __hip_atomic_load(&src[(b0 + bb) * H + tid],
                                                  __ATOMIC_RELAXED, __HIP_MEMORY_SCOPE_AGENT);
                        ok = ok && ((unsigned)(v[bb] >> 32) == (unsigned)t);
                    }
                    if (ok) break;
                    __builtin_amdgcn_s_sleep(1);
                }
                #pragma unroll
                for (int bb = 0; bb < GB; ++bb) hv[bb] = __uint_as_float((unsigned)v[bb]);
            }
            #pragma unroll
            for (int bb = 0; bb < GB; ++bb) {
                float tdv = tdlv[(b0 + bb) * T + t];
                float dec = __expf(-fmaxf(tdv * hdwk + hdbk, 0.f));
                hdec[bb][(tid >> 4) * 17 + (tid & 15)] = hv[bb] * dec;
            }
        }
        __syncthreads();

        // ---- (c) gh partial dot products from LDS ----
        #pragma unroll
        for (int bb = 0; bb < GB; ++bb) {
            float a0 = pr[bb], a1 = pz[bb], a3 = 0.f;
            #pragma unroll
            for (int j = 0; j < 16; ++j) {
                float hv = hdec[bb][kc * 17 + j];
                a0 = fmaf(whr[j], hv, a0);
                a1 = fmaf(whz[j], hv, a1);
                a3 = fmaf(whn[j], hv, a3);
            }
            pr[bb] = a0; pz[bb] = a1; pnh[bb] = a3;
        }

        // ---- (d) butterfly reduce over the 16 k-chunk lanes ----
        #pragma unroll
        for (int m = 1; m < 16; m <<= 1) {
            #pragma unroll
            for (int bb = 0; bb < GB; ++bb) {
                pr[bb]  += __shfl_xor(pr[bb],  m, 64);
                pz[bb]  += __shfl_xor(pz[bb],  m, 64);
                pnx[bb] += __shfl_xor(pnx[bb], m, 64);
                pnh[bb] += __shfl_xor(pnh[bb], m, 64);
            }
        }

        // ---- (e) owner-lane epilogue: hnew + publish ----
        if (kc == 0) {
            unsigned long long* dst = hx + (size_t)(t & 1) * (B * H);
            const unsigned long long tag = ((unsigned long long)(unsigned)(t + 1)) << 32;
            #pragma unroll
            for (int bb = 0; bb < GB; ++bb) {
                float hd = hdec[bb][kb * 17 + u_loc];
                float r = sigmoidf_(pr[bb] + br);
                float z = sigmoidf_(pz[bb] + bz);
                float n = tanhf_(pnx[bb] + bnx + r * (pnh[bb] + bnh));
                float hnew = (1.f - z) * n + z * hd;
                out[(size_t)((b0 + bb) * T + t) * H + row] = hnew;
                hown[bb][u_loc] = hnew;
                __hip_atomic_store(&dst[(b0 + bb) * H + row],
                                   tag | (unsigned long long)__float_as_uint(hnew),
                                   __ATOMIC_RELAXED, __HIP_MEMORY_SCOPE_AGENT);
                if (t == T - 1)
                    out[(size_t)B * T * H + (b0 + bb) * H + row] = hnew;
            }
        }
        __syncthreads();   // protects hdec/hown for next step's staging
    }
}

extern "C" void kernel_launch(void* const* d_in, const int* in_sizes, int n_in,
                              void* d_out, int out_size, void* d_ws, size_t ws_size,
                              hipStream_t stream) {
    (void)in_sizes; (void)n_in; (void)out_size; (void)ws_size;
    const float* x    = (const float*)d_in[0];
    const int*   mask = (const int*)d_in[1];
    const float* ts   = (const float*)d_in[2];
    const float* it0  = (const float*)d_in[3];
    const float* w_ih = (const float*)d_in[4];
    const float* w_hh = (const float*)d_in[5];
    const float* b_ih = (const float*)d_in[6];
    const float* b_hh = (const float*)d_in[7];
    const float* idw  = (const float*)d_in[8];
    const float* idb  = (const float*)d_in[9];
    const float* hdw  = (const float*)d_in[10];
    const float* hdb  = (const float*)d_in[11];
    float* out = (float*)d_out;

    // Workspace layout (bytes)
    char* ws = (char*)d_ws;
    float* xf   = (float*)(ws);                              // 33554432 B
    float* tdlv = (float*)(ws + 33554432);                   // 262144 B
    float* mean = (float*)(ws + 33816576);                   // 32768 B
    unsigned long long* hx = (unsigned long long*)(ws + 33849344); // 2*B*H u64 = 262144 B

    // d_out used as scratch before the RNN overwrites it entirely:
    float* ffill  = out;
    float* idelta = out + (size_t)B * T * D;

    // zero tag words each launch (stale tags from a previous replay could
    // otherwise alias a sought tag)
    hipMemsetAsync(hx, 0, (size_t)(2 * B * H) * 8, stream);

    prep_scan<<<B, D, 0, stream>>>(x, mask, ts, it0, ffill, idelta, mean, tdlv);
    fill_kernel<<<(B * T) / ROWS, 256, 0, stream>>>(x, mask, ffill, idelta, mean, idw, idb, xf);
    rnn_kernel<<<NG * GK, 256, 0, stream>>>(xf, tdlv, w_ih, w_hh, b_ih, b_hh, hdw, hdb,
                                            hx, out);
}

// Round 3
// 2897.315 us; speedup vs baseline: 5.1761x; 1.6005x over previous
//
#include <hip/hip_runtime.h>

// Problem constants
constexpr int B = 64, T = 1024, D = 128, H = 256;
// RNN partition: 64 groups (1 batch each) x 4 blocks; 64 units per block.
constexpr int NG = 64;   // groups
constexpr int GK = 4;    // blocks per group
constexpr int UO = 64;   // hidden units owned per block

__device__ __forceinline__ float sigmoidf_(float v) {
    return 1.f / (1.f + __expf(-v));
}
__device__ __forceinline__ float tanhf_(float v) {
    float e2 = __expf(2.f * v);
    return 1.f - 2.f / (e2 + 1.f);
}

// ---------------- P1: per-(b,d) scan over t (prefetch-unrolled) ----------------
__global__ __launch_bounds__(64) void prep_scan(
    const float* __restrict__ x, const int* __restrict__ mask,
    const float* __restrict__ ts, const float* __restrict__ it0,
    float* __restrict__ ffill, float* __restrict__ idelta,
    float* __restrict__ mean, float* __restrict__ tdlv)
{
    const int b = blockIdx.x;
    const int d = blockIdx.y * 64 + threadIdx.x;
    float prev_x = 0.f, prev_td = 0.f, osum = 0.f, mcnt = 0.f;
    float prev_ts = it0[b];               // init_time is (1,B) -> flat[b]
    const int baseT = b * T;
    constexpr int U = 16;
    for (int t0 = 0; t0 < T; t0 += U) {
        float xv[U]; int mv[U]; float tsv[U];
        #pragma unroll
        for (int u = 0; u < U; ++u) {
            const int idx = (baseT + t0 + u) * D + d;
            xv[u] = x[idx];
            mv[u] = mask[idx];
        }
        #pragma unroll
        for (int u = 0; u < U; ++u) tsv[u] = ts[baseT + t0 + u];
        #pragma unroll
        for (int u = 0; u < U; ++u) {
            const float td = tsv[u] - prev_ts;
            prev_ts = tsv[u];
            const int idx = (baseT + t0 + u) * D + d;
            if (!mv[u]) { prev_x = xv[u]; osum += xv[u]; } else { mcnt += 1.f; }
            prev_td += td;
            ffill[idx]  = prev_x;
            idelta[idx] = prev_td;
            if (!mv[u]) prev_td = 0.f;
            if (d == 0) tdlv[baseT + t0 + u] = logf(fminf(fmaxf(td, 0.f), 1000.f));
        }
    }
    mean[b * D + d] = osum / fmaxf(mcnt, 1.f);
}

// ---------------- P2: imputation matvec ----------------
constexpr int ROWS = 64;   // (b,t) rows per block
__global__ __launch_bounds__(256) void fill_kernel(
    const float* __restrict__ x, const int* __restrict__ mask,
    const float* __restrict__ ffill, const float* __restrict__ idelta,
    const float* __restrict__ mean, const float* __restrict__ idw,
    const float* __restrict__ idb, float* __restrict__ xf)
{
    __shared__ float widw[128 * 129];   // padded: conflict-free
    __shared__ float ide[2][128];
    const int tid = threadIdx.x;
    for (int i = tid; i < 128 * 128; i += 256)
        widw[(i >> 7) * 129 + (i & 127)] = idw[i];
    __syncthreads();
    const int p = tid >> 7, d = tid & 127;
    const float bias = idb[d];
    const int row0 = blockIdx.x * ROWS;
    for (int r = 0; r < ROWS; r += 2) {
        const int rowp = row0 + r + p;    // b*T + t
        const int idx = rowp * D + d;
        ide[p][d] = fminf(fmaxf(idelta[idx] - 1.f, 0.f), 1000.f);
        __syncthreads();
        float acc = bias;
        #pragma unroll
        for (int k = 0; k < 128; ++k)
            acc = fmaf(ide[p][k], widw[d * 129 + k], acc);
        float fw = __expf(-fmaxf(acc, 0.f));
        float filled = ffill[idx] * fw + (1.f - fw) * mean[(rowp >> 10) * D + d];
        xf[idx] = mask[idx] ? filled : x[idx];
        __syncthreads();
    }
}

// ---------------- P3: persistent grouped GRU-D recurrence ----------------
// 64 independent groups (1 batch each) of 4 blocks. Fence-free tagged 64-bit
// LLC exchange (tag = step+1 | f32 bits), double-buffered by step parity.
// Single barrier per step: hdec is parity-double-buffered and the owner lane
// pre-stages its own unit's decayed h for step t+1 (decay factor depends only
// on t+1, not on other units).
__global__ __launch_bounds__(256, 1) void rnn_kernel(
    const float* __restrict__ xf, const float* __restrict__ tdlv,
    const float* __restrict__ w_ih, const float* __restrict__ w_hh,
    const float* __restrict__ b_ih, const float* __restrict__ b_hh,
    const float* __restrict__ hdw, const float* __restrict__ hdb,
    unsigned long long* __restrict__ hx, float* __restrict__ out)
{
    const int tid = threadIdx.x;
    const int g  = blockIdx.x & (NG - 1);   // group = batch
    const int kb = blockIdx.x >> 6;         // owns units [kb*64, kb*64+64)
    const int u_loc = tid >> 2;             // 0..63
    const int kc = tid & 3;                 // k-chunk 0..3
    const int row = kb * UO + u_loc;        // owned hidden unit
    const int b = g;                        // batch

    // Weight-stationary register slices: h-k chunk = 64, x-k chunk = 32
    float whr[64], whz[64], whn[64];
    #pragma unroll
    for (int j = 0; j < 64; ++j) {
        whr[j] = w_hh[(row        ) * H + kc * 64 + j];
        whz[j] = w_hh[(row +     H) * H + kc * 64 + j];
        whn[j] = w_hh[(row + 2 * H) * H + kc * 64 + j];
    }
    float wir[32], wiz[32], win_[32];
    #pragma unroll
    for (int j = 0; j < 32; ++j) {
        wir[j]  = w_ih[(row        ) * D + kc * 32 + j];
        wiz[j]  = w_ih[(row +     H) * D + kc * 32 + j];
        win_[j] = w_ih[(row + 2 * H) * D + kc * 32 + j];
    }
    const bool ownk = ((tid >> 6) == kb);   // staged unit k=tid is block-local
    const float hdwk = hdw[tid];            // decay params for staged unit
    const float hdbk = hdb[tid];
    const float hdwo = hdw[row];            // decay params for owned unit
    const float hdbo = hdb[row];
    float br = 0.f, bz = 0.f, bnx = 0.f, bnh = 0.f;
    if (kc == 0) {
        br  = b_ih[row] + b_hh[row];
        bz  = b_ih[H + row] + b_hh[H + row];
        bnx = b_ih[2 * H + row];
        bnh = b_hh[2 * H + row];
    }

    __shared__ float hdec[2][H];   // decayed h, parity double-buffered
    hdec[0][tid] = 0.f;            // h0 = 0 (decayed 0 is 0)
    __syncthreads();

    const float* tdlb = tdlv + b * T;

    for (int t = 0; t < T; ++t) {
        const int par = t & 1;

        // ---- (a) prefetch-probe the remote tag word (hide under gi) ----
        const bool need = (t > 0) && !ownk;
        const unsigned long long* slot =
            hx + (size_t)((t - 1) & 1) * (B * H) + b * H + tid;
        unsigned long long v = 0;
        if (need)
            v = __hip_atomic_load(slot, __ATOMIC_RELAXED, __HIP_MEMORY_SCOPE_AGENT);

        // ---- (b) gi partials: independent of h ----
        const float4* xp4 = (const float4*)(xf + (size_t)(b * T + t) * D + kc * 32);
        float a0 = 0.f, a1 = 0.f, a2 = 0.f;
        #pragma unroll
        for (int i = 0; i < 8; ++i) {
            float4 xq = xp4[i];
            a0 = fmaf(wir[4*i  ], xq.x, a0); a1 = fmaf(wiz[4*i  ], xq.x, a1); a2 = fmaf(win_[4*i  ], xq.x, a2);
            a0 = fmaf(wir[4*i+1], xq.y, a0); a1 = fmaf(wiz[4*i+1], xq.y, a1); a2 = fmaf(win_[4*i+1], xq.y, a2);
            a0 = fmaf(wir[4*i+2], xq.z, a0); a1 = fmaf(wiz[4*i+2], xq.z, a1); a2 = fmaf(win_[4*i+2], xq.z, a2);
            a0 = fmaf(wir[4*i+3], xq.w, a0); a1 = fmaf(wiz[4*i+3], xq.w, a1); a2 = fmaf(win_[4*i+3], xq.w, a2);
        }

        // ---- (c) finish poll + stage decayed remote h into LDS ----
        if (need) {
            while ((unsigned)(v >> 32) != (unsigned)t)
                v = __hip_atomic_load(slot, __ATOMIC_RELAXED, __HIP_MEMORY_SCOPE_AGENT);
            float hv = __uint_as_float((unsigned)v);
            float dec = __expf(-fmaxf(tdlb[t] * hdwk + hdbk, 0.f));
            hdec[par][tid] = hv * dec;
        }
        __syncthreads();

        // ---- (d) gh partials from LDS ----
        float a3 = 0.f;
        const float4* hp4 = (const float4*)(&hdec[par][kc * 64]);
        #pragma unroll
        for (int i = 0; i < 16; ++i) {
            float4 hq = hp4[i];
            a0 = fmaf(whr[4*i  ], hq.x, a0); a1 = fmaf(whz[4*i  ], hq.x, a1); a3 = fmaf(whn[4*i  ], hq.x, a3);
            a0 = fmaf(whr[4*i+1], hq.y, a0); a1 = fmaf(whz[4*i+1], hq.y, a1); a3 = fmaf(whn[4*i+1], hq.y, a3);
            a0 = fmaf(whr[4*i+2], hq.z, a0); a1 = fmaf(whz[4*i+2], hq.z, a1); a3 = fmaf(whn[4*i+2], hq.z, a3);
            a0 = fmaf(whr[4*i+3], hq.w, a0); a1 = fmaf(whz[4*i+3], hq.w, a1); a3 = fmaf(whn[4*i+3], hq.w, a3);
        }

        // ---- (e) butterfly reduce over the 4 k-chunk lanes ----
        #pragma unroll
        for (int m = 1; m < 4; m <<= 1) {
            a0 += __shfl_xor(a0, m, 64);
            a1 += __shfl_xor(a1, m, 64);
            a2 += __shfl_xor(a2, m, 64);
            a3 += __shfl_xor(a3, m, 64);
        }

        // ---- (f) owner-lane epilogue: hnew, publish first, then stores ----
        if (kc == 0) {
            float hd = hdec[par][row];
            float r = sigmoidf_(a0 + br);
            float z = sigmoidf_(a1 + bz);
            float n = tanhf_(a2 + bnx + r * (a3 + bnh));
            float hnew = (1.f - z) * n + z * hd;
            // publish to LLC (tag = t+1) -- first, so it leaves immediately
            __hip_atomic_store(hx + (size_t)par * (B * H) + b * H + row,
                               (((unsigned long long)(unsigned)(t + 1)) << 32) |
                               (unsigned long long)__float_as_uint(hnew),
                               __ATOMIC_RELAXED, __HIP_MEMORY_SCOPE_AGENT);
            // pre-stage own unit's decayed h for step t+1 (no barrier needed:
            // readers of hdec[par^1] only run after next step's barrier)
            if (t + 1 < T) {
                float dec = __expf(-fmaxf(tdlb[t + 1] * hdwo + hdbo, 0.f));
                hdec[par ^ 1][row] = hnew * dec;
            }
            out[(size_t)(b * T + t) * H + row] = hnew;
            if (t == T - 1)
                out[(size_t)B * T * H + b * H + row] = hnew;
        }
        // no end-of-step barrier: hdec is parity-buffered; next step's staging
        // writes only remote slots (disjoint from owner-written own slots), and
        // the next __syncthreads orders all of it before the reads.
    }
}

extern "C" void kernel_launch(void* const* d_in, const int* in_sizes, int n_in,
                              void* d_out, int out_size, void* d_ws, size_t ws_size,
                              hipStream_t stream) {
    (void)in_sizes; (void)n_in; (void)out_size; (void)ws_size;
    const float* x    = (const float*)d_in[0];
    const int*   mask = (const int*)d_in[1];
    const float* ts   = (const float*)d_in[2];
    const float* it0  = (const float*)d_in[3];
    const float* w_ih = (const float*)d_in[4];
    const float* w_hh = (const float*)d_in[5];
    const float* b_ih = (const float*)d_in[6];
    const float* b_hh = (const float*)d_in[7];
    const float* idw  = (const float*)d_in[8];
    const float* idb  = (const float*)d_in[9];
    const float* hdw  = (const float*)d_in[10];
    const float* hdb  = (const float*)d_in[11];
    float* out = (float*)d_out;

    // Workspace layout (bytes)
    char* ws = (char*)d_ws;
    float* xf   = (float*)(ws);                              // 33554432 B
    float* tdlv = (float*)(ws + 33554432);                   // 262144 B
    float* mean = (float*)(ws + 33816576);                   // 32768 B
    unsigned long long* hx = (unsigned long long*)(ws + 33849344); // 2*B*H u64

    // d_out used as scratch before the RNN overwrites it entirely:
    float* ffill  = out;
    float* idelta = out + (size_t)B * T * D;

    // zero tag words each launch (replay safety)
    hipMemsetAsync(hx, 0, (size_t)(2 * B * H) * 8, stream);

    prep_scan<<<dim3(B, 2), 64, 0, stream>>>(x, mask, ts, it0, ffill, idelta, mean, tdlv);
    fill_kernel<<<(B * T) / ROWS, 256, 0, stream>>>(x, mask, ffill, idelta, mean, idw, idb, xf);
    rnn_kernel<<<NG * GK, 256, 0, stream>>>(xf, tdlv, w_ih, w_hh, b_ih, b_hh, hdw, hdb,
                                            hx, out);
}

// Round 4
// 1879.035 us; speedup vs baseline: 7.9811x; 1.5419x over previous
//
#include <hip/hip_runtime.h>

// Problem constants
constexpr int B = 64, T = 1024, D = 128, H = 256;
// RNN partition: 64 groups (1 batch each) x 4 blocks of 512 threads.
// Each block owns 64 units; 8 lanes (k-chunks) per unit -> 144 weight floats/thread.
constexpr int NG = 64;   // groups
constexpr int GK = 4;    // blocks per group
constexpr int UO = 64;   // hidden units owned per block
constexpr int CS = 40;   // hdec chunk stride in floats (32 data + 8 skew; 16B-aligned)

__device__ __forceinline__ float sigmoidf_(float v) {
    return 1.f / (1.f + __expf(-v));
}
__device__ __forceinline__ float tanhf_(float v) {
    float e2 = __expf(2.f * v);
    return 1.f - 2.f / (e2 + 1.f);
}

// ---------------- P1: per-(b,d) scan over t (prefetch-unrolled) ----------------
__global__ __launch_bounds__(64) void prep_scan(
    const float* __restrict__ x, const int* __restrict__ mask,
    const float* __restrict__ ts, const float* __restrict__ it0,
    float* __restrict__ ffill, float* __restrict__ idelta,
    float* __restrict__ mean, float* __restrict__ tdlv)
{
    const int b = blockIdx.x;
    const int d = blockIdx.y * 64 + threadIdx.x;
    float prev_x = 0.f, prev_td = 0.f, osum = 0.f, mcnt = 0.f;
    float prev_ts = it0[b];               // init_time is (1,B) -> flat[b]
    const int baseT = b * T;
    constexpr int U = 16;
    for (int t0 = 0; t0 < T; t0 += U) {
        float xv[U]; int mv[U]; float tsv[U];
        #pragma unroll
        for (int u = 0; u < U; ++u) {
            const int idx = (baseT + t0 + u) * D + d;
            xv[u] = x[idx];
            mv[u] = mask[idx];
        }
        #pragma unroll
        for (int u = 0; u < U; ++u) tsv[u] = ts[baseT + t0 + u];
        #pragma unroll
        for (int u = 0; u < U; ++u) {
            const float td = tsv[u] - prev_ts;
            prev_ts = tsv[u];
            const int idx = (baseT + t0 + u) * D + d;
            if (!mv[u]) { prev_x = xv[u]; osum += xv[u]; } else { mcnt += 1.f; }
            prev_td += td;
            ffill[idx]  = prev_x;
            idelta[idx] = prev_td;
            if (!mv[u]) prev_td = 0.f;
            if (d == 0) tdlv[baseT + t0 + u] = logf(fminf(fmaxf(td, 0.f), 1000.f));
        }
    }
    mean[b * D + d] = osum / fmaxf(mcnt, 1.f);
}

// ---------------- P2: imputation matvec ----------------
constexpr int ROWS = 64;   // (b,t) rows per block
__global__ __launch_bounds__(256) void fill_kernel(
    const float* __restrict__ x, const int* __restrict__ mask,
    const float* __restrict__ ffill, const float* __restrict__ idelta,
    const float* __restrict__ mean, const float* __restrict__ idw,
    const float* __restrict__ idb, float* __restrict__ xf)
{
    __shared__ float widw[128 * 129];   // padded: conflict-free
    __shared__ float ide[2][128];
    const int tid = threadIdx.x;
    for (int i = tid; i < 128 * 128; i += 256)
        widw[(i >> 7) * 129 + (i & 127)] = idw[i];
    __syncthreads();
    const int p = tid >> 7, d = tid & 127;
    const float bias = idb[d];
    const int row0 = blockIdx.x * ROWS;
    for (int r = 0; r < ROWS; r += 2) {
        const int rowp = row0 + r + p;    // b*T + t
        const int idx = rowp * D + d;
        ide[p][d] = fminf(fmaxf(idelta[idx] - 1.f, 0.f), 1000.f);
        __syncthreads();
        float acc = bias;
        #pragma unroll
        for (int k = 0; k < 128; ++k)
            acc = fmaf(ide[p][k], widw[d * 129 + k], acc);
        float fw = __expf(-fmaxf(acc, 0.f));
        float filled = ffill[idx] * fw + (1.f - fw) * mean[(rowp >> 10) * D + d];
        xf[idx] = mask[idx] ? filled : x[idx];
        __syncthreads();
    }
}

// ---------------- P3: persistent grouped GRU-D recurrence ----------------
// 64 independent groups (1 batch each) of 4 blocks x 512 threads. Fence-free
// tagged 64-bit LLC exchange (tag = step+1 | f32 bits), parity double-buffered.
// One barrier per step; hdec parity-buffered with skewed chunk stride (CS=40)
// so the gh ds_read_b128 pattern is at worst 2-way bank-aliased (free).
__global__ __launch_bounds__(512, 2) void rnn_kernel(
    const float* __restrict__ xf, const float* __restrict__ tdlv,
    const float* __restrict__ w_ih, const float* __restrict__ w_hh,
    const float* __restrict__ b_ih, const float* __restrict__ b_hh,
    const float* __restrict__ hdw, const float* __restrict__ hdb,
    unsigned long long* __restrict__ hx, float* __restrict__ out)
{
    const int tid = threadIdx.x;
    const int g  = blockIdx.x & (NG - 1);   // group = batch (members same XCD mod 8)
    const int kb = blockIdx.x >> 6;         // owns units [kb*64, kb*64+64)
    const int u_loc = tid >> 3;             // 0..63
    const int kc = tid & 7;                 // k-chunk 0..7
    const int row = kb * UO + u_loc;        // owned hidden unit
    const int b = g;                        // batch

    // Weight-stationary register slices: gh chunk = 32, gi chunk = 16
    float whr[32], whz[32], whn[32];
    #pragma unroll
    for (int j = 0; j < 32; ++j) {
        whr[j] = w_hh[(row        ) * H + kc * 32 + j];
        whz[j] = w_hh[(row +     H) * H + kc * 32 + j];
        whn[j] = w_hh[(row + 2 * H) * H + kc * 32 + j];
    }
    float wir[16], wiz[16], win_[16];
    #pragma unroll
    for (int j = 0; j < 16; ++j) {
        wir[j]  = w_ih[(row        ) * D + kc * 16 + j];
        wiz[j]  = w_ih[(row +     H) * D + kc * 16 + j];
        win_[j] = w_ih[(row + 2 * H) * D + kc * 16 + j];
    }
    // Staging role: threads 0..255 stage unit k = tid
    const bool stager = (tid < H);
    const bool ownk = stager && ((tid >> 6) == kb);
    const float hdwk = stager ? hdw[tid] : 0.f;
    const float hdbk = stager ? hdb[tid] : 0.f;
    const float hdwo = hdw[row];            // decay params for owned unit
    const float hdbo = hdb[row];
    float br = 0.f, bz = 0.f, bnx = 0.f, bnh = 0.f;
    if (kc == 0) {
        br  = b_ih[row] + b_hh[row];
        bz  = b_ih[H + row] + b_hh[H + row];
        bnx = b_ih[2 * H + row];
        bnh = b_hh[2 * H + row];
    }

    __shared__ float hdec[2][8 * CS];   // decayed h, parity buffered, skewed
    for (int i = tid; i < 2 * 8 * CS; i += 512)
        ((float*)hdec)[i] = 0.f;        // h0 = 0 (decayed 0 is 0)
    __syncthreads();

    const float* tdlb = tdlv + b * T;

    for (int t = 0; t < T; ++t) {
        const int par = t & 1;

        // ---- (a) prefetch-probe the remote tag word (hide under gi) ----
        const bool need = (t > 0) && stager && !ownk;
        const unsigned long long* slot =
            hx + (size_t)((t - 1) & 1) * (B * H) + b * H + tid;
        unsigned long long v = 0;
        if (need)
            v = __hip_atomic_load(slot, __ATOMIC_RELAXED, __HIP_MEMORY_SCOPE_AGENT);

        // ---- (b) gi partials: independent of h ----
        const float4* xp4 = (const float4*)(xf + (size_t)(b * T + t) * D + kc * 16);
        float a0 = 0.f, a1 = 0.f, a2 = 0.f;
        #pragma unroll
        for (int i = 0; i < 4; ++i) {
            float4 xq = xp4[i];
            a0 = fmaf(wir[4*i  ], xq.x, a0); a1 = fmaf(wiz[4*i  ], xq.x, a1); a2 = fmaf(win_[4*i  ], xq.x, a2);
            a0 = fmaf(wir[4*i+1], xq.y, a0); a1 = fmaf(wiz[4*i+1], xq.y, a1); a2 = fmaf(win_[4*i+1], xq.y, a2);
            a0 = fmaf(wir[4*i+2], xq.z, a0); a1 = fmaf(wiz[4*i+2], xq.z, a1); a2 = fmaf(win_[4*i+2], xq.z, a2);
            a0 = fmaf(wir[4*i+3], xq.w, a0); a1 = fmaf(wiz[4*i+3], xq.w, a1); a2 = fmaf(win_[4*i+3], xq.w, a2);
        }

        // ---- (c) finish poll + stage decayed remote h into LDS ----
        if (need) {
            while ((unsigned)(v >> 32) != (unsigned)t)
                v = __hip_atomic_load(slot, __ATOMIC_RELAXED, __HIP_MEMORY_SCOPE_AGENT);
            float hv = __uint_as_float((unsigned)v);
            float dec = __expf(-fmaxf(tdlb[t] * hdwk + hdbk, 0.f));
            hdec[par][(tid >> 5) * CS + (tid & 31)] = hv * dec;
        }
        __syncthreads();

        // ---- (d) gh partials from LDS (skewed chunks: conflict-free-ish) ----
        float a3 = 0.f;
        const float4* hp4 = (const float4*)(&hdec[par][kc * CS]);
        #pragma unroll
        for (int i = 0; i < 8; ++i) {
            float4 hq = hp4[i];
            a0 = fmaf(whr[4*i  ], hq.x, a0); a1 = fmaf(whz[4*i  ], hq.x, a1); a3 = fmaf(whn[4*i  ], hq.x, a3);
            a0 = fmaf(whr[4*i+1], hq.y, a0); a1 = fmaf(whz[4*i+1], hq.y, a1); a3 = fmaf(whn[4*i+1], hq.y, a3);
            a0 = fmaf(whr[4*i+2], hq.z, a0); a1 = fmaf(whz[4*i+2], hq.z, a1); a3 = fmaf(whn[4*i+2], hq.z, a3);
            a0 = fmaf(whr[4*i+3], hq.w, a0); a1 = fmaf(whz[4*i+3], hq.w, a1); a3 = fmaf(whn[4*i+3], hq.w, a3);
        }

        // ---- (e) butterfly reduce over the 8 k-chunk lanes ----
        #pragma unroll
        for (int m = 1; m < 8; m <<= 1) {
            a0 += __shfl_xor(a0, m, 64);
            a1 += __shfl_xor(a1, m, 64);
            a2 += __shfl_xor(a2, m, 64);
            a3 += __shfl_xor(a3, m, 64);
        }

        // ---- (f) owner-lane epilogue: hnew, publish first, then stores ----
        if (kc == 0) {
            float hd = hdec[par][(row >> 5) * CS + (row & 31)];
            float r = sigmoidf_(a0 + br);
            float z = sigmoidf_(a1 + bz);
            float n = tanhf_(a2 + bnx + r * (a3 + bnh));
            float hnew = (1.f - z) * n + z * hd;
            // publish to LLC (tag = t+1) -- first, so the store leaves now
            __hip_atomic_store(hx + (size_t)par * (B * H) + b * H + row,
                               (((unsigned long long)(unsigned)(t + 1)) << 32) |
                               (unsigned long long)__float_as_uint(hnew),
                               __ATOMIC_RELAXED, __HIP_MEMORY_SCOPE_AGENT);
            // pre-stage own unit's decayed h for step t+1 (readers of
            // hdec[par^1] only run after next step's barrier)
            if (t + 1 < T) {
                float dec = __expf(-fmaxf(tdlb[t + 1] * hdwo + hdbo, 0.f));
                hdec[par ^ 1][(row >> 5) * CS + (row & 31)] = hnew * dec;
            }
            out[(size_t)(b * T + t) * H + row] = hnew;
            if (t == T - 1)
                out[(size_t)B * T * H + b * H + row] = hnew;
        }
        // no end-of-step barrier: parity buffering + next step's barrier
        // order all hdec writes before their reads (see analysis).
    }
}

extern "C" void kernel_launch(void* const* d_in, const int* in_sizes, int n_in,
                              void* d_out, int out_size, void* d_ws, size_t ws_size,
                              hipStream_t stream) {
    (void)in_sizes; (void)n_in; (void)out_size; (void)ws_size;
    const float* x    = (const float*)d_in[0];
    const int*   mask = (const int*)d_in[1];
    const float* ts   = (const float*)d_in[2];
    const float* it0  = (const float*)d_in[3];
    const float* w_ih = (const float*)d_in[4];
    const float* w_hh = (const float*)d_in[5];
    const float* b_ih = (const float*)d_in[6];
    const float* b_hh = (const float*)d_in[7];
    const float* idw  = (const float*)d_in[8];
    const float* idb  = (const float*)d_in[9];
    const float* hdw  = (const float*)d_in[10];
    const float* hdb  = (const float*)d_in[11];
    float* out = (float*)d_out;

    // Workspace layout (bytes)
    char* ws = (char*)d_ws;
    float* xf   = (float*)(ws);                              // 33554432 B
    float* tdlv = (float*)(ws + 33554432);                   // 262144 B
    float* mean = (float*)(ws + 33816576);                   // 32768 B
    unsigned long long* hx = (unsigned long long*)(ws + 33849344); // 2*B*H u64

    // d_out used as scratch before the RNN overwrites it entirely:
    float* ffill  = out;
    float* idelta = out + (size_t)B * T * D;

    // zero tag words each launch (replay safety)
    hipMemsetAsync(hx, 0, (size_t)(2 * B * H) * 8, stream);

    prep_scan<<<dim3(B, 2), 64, 0, stream>>>(x, mask, ts, it0, ffill, idelta, mean, tdlv);
    fill_kernel<<<(B * T) / ROWS, 256, 0, stream>>>(x, mask, ffill, idelta, mean, idw, idb, xf);
    rnn_kernel<<<NG * GK, 512, 0, stream>>>(xf, tdlv, w_ih, w_hh, b_ih, b_hh, hdw, hdb,
                                            hx, out);
}